// Round 7
// baseline (769.026 us; speedup 1.0000x reference)
//
#include <hip/hip_runtime.h>
#include <hip/hip_bf16.h>

// Problem constants (shapes fixed by setup_inputs). All float I/O is fp32
// (established round 4: hardcoded-bf16 reads NaN'd twice; flag-version passed).
#define F_IN  500
#define HC    128   // H*C
#define NHEAD 8
#define CDIM  16
#define NCLS  16
#define KPAD  512   // F_IN padded to multiple of 32 for MFMA K-loop

static __device__ __forceinline__ float bf(const __hip_bfloat16 v) {
    return __bfloat162float(v);
}

// ordered-uint encoding for float atomicMax
static __device__ __forceinline__ unsigned int enc_f32(float f) {
    unsigned int u = __float_as_uint(f);
    return (u & 0x80000000u) ? ~u : (u | 0x80000000u);
}
static __device__ __forceinline__ float dec_f32(unsigned int u) {
    return __uint_as_float((u & 0x80000000u) ? (u & 0x7FFFFFFFu) : ~u);
}

typedef __bf16 bf16x8 __attribute__((ext_vector_type(8)));
typedef float f32x4 __attribute__((ext_vector_type(4)));

// ---------------------------------------------------------------- zero fill (ints)
__global__ void zero_i32(int* __restrict__ p, int n) {
    int i = blockIdx.x * blockDim.x + threadIdx.x;
    if (i < n) p[i] = 0;
}

// ---------------------------------------------------------------- W1^T prep:
// w1t_hi[c][k] = bf16(W1[k][c]), w1t_lo = bf16(residual); zero-padded k>=500.
__global__ void transpose_w1(const float* __restrict__ W1,
                             __bf16* __restrict__ w1t_hi,
                             __bf16* __restrict__ w1t_lo)
{
    int id = blockIdx.x * 256 + threadIdx.x;   // 128*512
    int c = id >> 9, k = id & 511;
    float v = (k < F_IN) ? W1[k * HC + c] : 0.f;
    __bf16 h = (__bf16)v;
    w1t_hi[id] = h;
    w1t_lo[id] = (__bf16)(v - (float)h);
}

// split 8 fp32 into bf16 hi + bf16 lo fragments
static __device__ __forceinline__ void split8(const float4 a, const float4 b,
                                              bf16x8& hi, bf16x8& lo) {
    float v[8] = {a.x, a.y, a.z, a.w, b.x, b.y, b.z, b.w};
#pragma unroll
    for (int j = 0; j < 8; j++) {
        __bf16 h = (__bf16)v[j];
        hi[j] = h;
        lo[j] = (__bf16)(v[j] - (float)h);
    }
}

// ---------------------------------------------------------------- GEMM1 (MFMA, split-bf16):
// h1 = x @ W1 -> bf16 [N,128]. Block = 4 waves over 32 rows; wave w owns col
// tiles 2w,2w+1 (32 cols). All 4 waves load the same A addresses (L2/MSHR
// dedup); per-wave serial chain is 4x shorter than the all-cols version and
// wave count is 4x higher (12500) -> latency hiding via occupancy.
// acc += Ah*Bh + Ah*Bl + Al*Bh  (error ~ lo*lo ~ 2^-16 rel).
__global__ __launch_bounds__(256) void gemm1_mfma(
    const float* __restrict__ x,
    const __bf16* __restrict__ w1t_hi, const __bf16* __restrict__ w1t_lo,
    __hip_bfloat16* __restrict__ h1, int N)
{
    const int wave = threadIdx.x >> 6, lane = threadIdx.x & 63;
    const int m = lane & 15, q = lane >> 4;
    const int row0 = blockIdx.x * 32;

    long ra0 = row0 + m, ra1 = row0 + 16 + m;
    if (ra0 >= N) ra0 = 0;
    if (ra1 >= N) ra1 = 0;
    const float* pa0 = x + ra0 * F_IN + q * 8;
    const float* pa1 = x + ra1 * F_IN + q * 8;
    // wave's two col-tiles: t0 = 2*wave, t1 = 2*wave+1
    const __bf16* pbh0 = w1t_hi + (size_t)(2 * wave * 16 + m) * KPAD + q * 8;
    const __bf16* pbl0 = w1t_lo + (size_t)(2 * wave * 16 + m) * KPAD + q * 8;
    const __bf16* pbh1 = pbh0 + 16 * KPAD;
    const __bf16* pbl1 = pbl0 + 16 * KPAD;

    f32x4 acc[2][2];
#pragma unroll
    for (int i = 0; i < 2; i++)
#pragma unroll
        for (int t = 0; t < 2; t++) acc[i][t] = (f32x4){0.f, 0.f, 0.f, 0.f};

    // main K steps: k0 = 0..448 (max k touched = 448+31 = 479 < 500)
#pragma unroll
    for (int k0 = 0; k0 < 480; k0 += 32) {
        bf16x8 a0h, a0l, a1h, a1l;
        split8(*(const float4*)(pa0 + k0), *(const float4*)(pa0 + k0 + 4), a0h, a0l);
        split8(*(const float4*)(pa1 + k0), *(const float4*)(pa1 + k0 + 4), a1h, a1l);
        bf16x8 bh0 = *(const bf16x8*)(pbh0 + k0);
        bf16x8 bl0 = *(const bf16x8*)(pbl0 + k0);
        bf16x8 bh1 = *(const bf16x8*)(pbh1 + k0);
        bf16x8 bl1 = *(const bf16x8*)(pbl1 + k0);
        acc[0][0] = __builtin_amdgcn_mfma_f32_16x16x32_bf16(a0h, bh0, acc[0][0], 0, 0, 0);
        acc[0][0] = __builtin_amdgcn_mfma_f32_16x16x32_bf16(a0h, bl0, acc[0][0], 0, 0, 0);
        acc[0][0] = __builtin_amdgcn_mfma_f32_16x16x32_bf16(a0l, bh0, acc[0][0], 0, 0, 0);
        acc[1][0] = __builtin_amdgcn_mfma_f32_16x16x32_bf16(a1h, bh0, acc[1][0], 0, 0, 0);
        acc[1][0] = __builtin_amdgcn_mfma_f32_16x16x32_bf16(a1h, bl0, acc[1][0], 0, 0, 0);
        acc[1][0] = __builtin_amdgcn_mfma_f32_16x16x32_bf16(a1l, bh0, acc[1][0], 0, 0, 0);
        acc[0][1] = __builtin_amdgcn_mfma_f32_16x16x32_bf16(a0h, bh1, acc[0][1], 0, 0, 0);
        acc[0][1] = __builtin_amdgcn_mfma_f32_16x16x32_bf16(a0h, bl1, acc[0][1], 0, 0, 0);
        acc[0][1] = __builtin_amdgcn_mfma_f32_16x16x32_bf16(a0l, bh1, acc[0][1], 0, 0, 0);
        acc[1][1] = __builtin_amdgcn_mfma_f32_16x16x32_bf16(a1h, bh1, acc[1][1], 0, 0, 0);
        acc[1][1] = __builtin_amdgcn_mfma_f32_16x16x32_bf16(a1h, bl1, acc[1][1], 0, 0, 0);
        acc[1][1] = __builtin_amdgcn_mfma_f32_16x16x32_bf16(a1l, bh1, acc[1][1], 0, 0, 0);
    }
    // epilogue K step k0=480: lanes with k>=500 masked (W1^T already 0 there)
    {
        const float4 z4 = make_float4(0.f, 0.f, 0.f, 0.f);
        bf16x8 a0h, a0l, a1h, a1l;
        float4 u0 = (q < 3) ? *(const float4*)(pa0 + 480) : z4;
        float4 u1 = (q < 2) ? *(const float4*)(pa0 + 484) : z4;
        float4 w0 = (q < 3) ? *(const float4*)(pa1 + 480) : z4;
        float4 w1 = (q < 2) ? *(const float4*)(pa1 + 484) : z4;
        split8(u0, u1, a0h, a0l);
        split8(w0, w1, a1h, a1l);
        bf16x8 bh0 = *(const bf16x8*)(pbh0 + 480);
        bf16x8 bl0 = *(const bf16x8*)(pbl0 + 480);
        bf16x8 bh1 = *(const bf16x8*)(pbh1 + 480);
        bf16x8 bl1 = *(const bf16x8*)(pbl1 + 480);
        acc[0][0] = __builtin_amdgcn_mfma_f32_16x16x32_bf16(a0h, bh0, acc[0][0], 0, 0, 0);
        acc[0][0] = __builtin_amdgcn_mfma_f32_16x16x32_bf16(a0h, bl0, acc[0][0], 0, 0, 0);
        acc[0][0] = __builtin_amdgcn_mfma_f32_16x16x32_bf16(a0l, bh0, acc[0][0], 0, 0, 0);
        acc[1][0] = __builtin_amdgcn_mfma_f32_16x16x32_bf16(a1h, bh0, acc[1][0], 0, 0, 0);
        acc[1][0] = __builtin_amdgcn_mfma_f32_16x16x32_bf16(a1h, bl0, acc[1][0], 0, 0, 0);
        acc[1][0] = __builtin_amdgcn_mfma_f32_16x16x32_bf16(a1l, bh0, acc[1][0], 0, 0, 0);
        acc[0][1] = __builtin_amdgcn_mfma_f32_16x16x32_bf16(a0h, bh1, acc[0][1], 0, 0, 0);
        acc[0][1] = __builtin_amdgcn_mfma_f32_16x16x32_bf16(a0h, bl1, acc[0][1], 0, 0, 0);
        acc[0][1] = __builtin_amdgcn_mfma_f32_16x16x32_bf16(a0l, bh1, acc[0][1], 0, 0, 0);
        acc[1][1] = __builtin_amdgcn_mfma_f32_16x16x32_bf16(a1h, bh1, acc[1][1], 0, 0, 0);
        acc[1][1] = __builtin_amdgcn_mfma_f32_16x16x32_bf16(a1h, bl1, acc[1][1], 0, 0, 0);
        acc[1][1] = __builtin_amdgcn_mfma_f32_16x16x32_bf16(a1l, bh1, acc[1][1], 0, 0, 0);
    }
    // store: C/D layout col=lane&15, row=(lane>>4)*4+reg
#pragma unroll
    for (int rt = 0; rt < 2; rt++) {
        int rbase = row0 + rt * 16 + q * 4;
#pragma unroll
        for (int tt = 0; tt < 2; tt++) {
            int col = (2 * wave + tt) * 16 + m;
#pragma unroll
            for (int r = 0; r < 4; r++) {
                int row = rbase + r;
                if (row < N)
                    h1[(size_t)row * HC + col] = __float2bfloat16(acc[rt][tt][r]);
            }
        }
    }
}

// ---------------------------------------------------------------- per-node attention dots for layer 1
// d1[j*N*8 + n*8 + h] = sum_c h1[n,h,c] * a1[j,h,c]
__global__ void dots1_kernel(const __hip_bfloat16* __restrict__ h1,
                             const float* __restrict__ a1,
                             float* __restrict__ d1, int N)
{
    int id = blockIdx.x * blockDim.x + threadIdx.x;
    if (id >= N * NHEAD) return;
    int n = id >> 3, h = id & 7;
    const __hip_bfloat16* hp = h1 + (size_t)n * HC + h * CDIM;
    float s0 = 0.f, s1 = 0.f, s2 = 0.f;
#pragma unroll
    for (int c = 0; c < CDIM; c++) {
        float v = bf(hp[c]);
        s0 += v * a1[(0 * NHEAD + h) * CDIM + c];
        s1 += v * a1[(1 * NHEAD + h) * CDIM + c];
        s2 += v * a1[(2 * NHEAD + h) * CDIM + c];
    }
    d1[id] = s0;
    d1[N * NHEAD + id] = s1;
    d1[2 * N * NHEAD + id] = s2;
}

// ---------------------------------------------------------------- global maxima of d1m/d1t per head
__global__ void maxred_d1(const float* __restrict__ d1,
                          unsigned int* __restrict__ gmax, int N)
{
    __shared__ unsigned int sm[16];
    if (threadIdx.x < 16) sm[threadIdx.x] = 0;
    __syncthreads();
    int total = 2 * N * NHEAD;
    for (int i = blockIdx.x * blockDim.x + threadIdx.x; i < total;
         i += gridDim.x * blockDim.x) {
        float v = d1[(size_t)N * NHEAD + i];   // d1m region then d1t region
        int slot = ((i >= N * NHEAD) ? 8 : 0) + (i & 7);
        atomicMax(&sm[slot], enc_f32(v));
    }
    __syncthreads();
    if (threadIdx.x < 16) atomicMax(&gmax[threadIdx.x], sm[threadIdx.x]);
}

// gmax2[0] = max_n d2m[n]; gmax2[1] = max_n d2t[n]
__global__ void maxred_d2(const float* __restrict__ d2,
                          unsigned int* __restrict__ gmax2, int N)
{
    __shared__ unsigned int sm[2];
    if (threadIdx.x < 2) sm[threadIdx.x] = 0;
    __syncthreads();
    int total = 2 * N;
    for (int i = blockIdx.x * blockDim.x + threadIdx.x; i < total;
         i += gridDim.x * blockDim.x) {
        float v = d2[N + i];
        atomicMax(&sm[i >= N ? 1 : 0], enc_f32(v));
    }
    __syncthreads();
    if (threadIdx.x < 2) atomicMax(&gmax2[threadIdx.x], sm[threadIdx.x]);
}

// ---------------------------------------------------------------- CSR build
__global__ void hist_kernel(const int* __restrict__ pidx, int* __restrict__ deg, int P) {
    int p = blockIdx.x * blockDim.x + threadIdx.x;
    if (p < P) atomicAdd(deg + pidx[p], 1);
}

__global__ void scan1_kernel(const int* __restrict__ deg, int* __restrict__ start,
                             int* __restrict__ bsum, int N) {
    __shared__ int sh[256];
    int i = blockIdx.x * 256 + threadIdx.x;
    int v = (i < N) ? deg[i] : 0;
    sh[threadIdx.x] = v;
    __syncthreads();
#pragma unroll
    for (int off = 1; off < 256; off <<= 1) {
        int x = (threadIdx.x >= off) ? sh[threadIdx.x - off] : 0;
        __syncthreads();
        sh[threadIdx.x] += x;
        __syncthreads();
    }
    if (i < N) start[i] = sh[threadIdx.x] - v;   // exclusive
    if (threadIdx.x == 255) bsum[blockIdx.x] = sh[255];
}

__global__ void scan2_kernel(int* __restrict__ bsum, int nb) {
    __shared__ int sh[512];
    int v = (threadIdx.x < nb) ? bsum[threadIdx.x] : 0;
    sh[threadIdx.x] = v;
    __syncthreads();
#pragma unroll
    for (int off = 1; off < 512; off <<= 1) {
        int x = (threadIdx.x >= off) ? sh[threadIdx.x - off] : 0;
        __syncthreads();
        sh[threadIdx.x] += x;
        __syncthreads();
    }
    if (threadIdx.x < nb) bsum[threadIdx.x] = sh[threadIdx.x] - v;  // exclusive
}

__global__ void scan3_kernel(int* __restrict__ start, const int* __restrict__ bsum, int N) {
    int i = blockIdx.x * 256 + threadIdx.x;
    if (i < N) start[i] += bsum[blockIdx.x];
}

__global__ void scatter_kernel(const int* __restrict__ pidx,
                               const int* __restrict__ start,
                               int* __restrict__ cursor,
                               int* __restrict__ csr, int P) {
    int p = blockIdx.x * blockDim.x + threadIdx.x;
    if (p >= P) return;
    int hd = pidx[p];
    int pos = atomicAdd(cursor + hd, 1);
    csr[start[hd] + pos] = p;
}

// ---------------------------------------------------------------- layer1 attention, CSR, single pass.
// One wave per node; softmax shift = global upper bound (softmax invariant).
__global__ __launch_bounds__(256) void attn1_csr_kernel(
    const int* __restrict__ csr, const int* __restrict__ start,
    const int* __restrict__ deg, const int* __restrict__ pidx,
    const float* __restrict__ d1, const __hip_bfloat16* __restrict__ h1,
    const float* __restrict__ b1, const unsigned int* __restrict__ gmax,
    float* __restrict__ elu_out, int N, int P)
{
    int node = blockIdx.x * 4 + (threadIdx.x >> 6);
    if (node >= N) return;
    int lane = threadIdx.x & 63;
    int h = lane >> 3;
    int s0 = start[node], dg = deg[node];
    const float* d1m = d1 + (size_t)N * NHEAD;
    const float* d1t = d1 + (size_t)2 * N * NHEAD;
    const float dh = d1[node * NHEAD + h];
    float zub = dh + dec_f32(gmax[h]) + dec_f32(gmax[8 + h]);
    const float mxub = zub > 0.f ? zub : 0.2f * zub;

    float acc0 = 0.f, acc1 = 0.f, den = 0.f;
    for (int k0 = 0; k0 < dg; k0 += 8) {
        int kk = k0 + (lane & 7);
        bool valid = kk < dg;
        int p = csr[s0 + (valid ? kk : dg - 1)];
        int mid = pidx[P + p], tl = pidx[2 * P + p];
        float z = dh + d1m[mid * NHEAD + h] + d1t[tl * NHEAD + h];
        float e = z > 0.f ? z : 0.2f * z;
        float ex = valid ? __expf(e - mxub) : 0.f;
        den += ex;
        int kmax = dg - k0; if (kmax > 8) kmax = 8;
        for (int dk = 0; dk < kmax; dk++) {
            int tl_b = __shfl(tl, dk, 8);
            float ex_b = __shfl(ex, dk, 8);
            __hip_bfloat162 v = *(const __hip_bfloat162*)(h1 + (size_t)tl_b * HC + 2 * lane);
            acc0 += ex_b * bf(v.x);
            acc1 += ex_b * bf(v.y);
        }
    }
#pragma unroll
    for (int w = 1; w < 8; w <<= 1) den += __shfl_xor(den, w, 8);

    float inv = 1.f / (den + 1e-16f);
    int j0 = 2 * lane;
    float v0 = acc0 * inv + b1[j0];
    float v1 = acc1 * inv + b1[j0 + 1];
    v0 = v0 > 0.f ? v0 : __expf(v0) - 1.f;
    v1 = v1 > 0.f ? v1 : __expf(v1) - 1.f;
    *(float2*)(elu_out + (size_t)node * HC + j0) = make_float2(v0, v1);
}

// ---------------------------------------------------------------- layer2 GEMM + dots: h2 = elu @ W2 ; d2[j,n] = h2[n,:]·a2[j]
__global__ __launch_bounds__(256) void layer2_kernel(
    const float* __restrict__ elu, const float* __restrict__ W2,
    const float* __restrict__ a2,
    float* __restrict__ h2, float* __restrict__ d2, int N)
{
    __shared__ float rows[16][HC + 1];
    __shared__ float h2s[16][NCLS + 1];
    const int n0 = blockIdx.x * 16;
    const int tid = threadIdx.x;
    for (int idx = tid; idx < 16 * HC; idx += 256) {
        int r = idx >> 7, c = idx & 127;
        rows[r][c] = (n0 + r < N) ? elu[(size_t)(n0 + r) * HC + c] : 0.f;
    }
    __syncthreads();
    int ln = tid >> 4, c = tid & 15;
    float acc = 0.f;
#pragma unroll 8
    for (int j = 0; j < HC; j++) acc += rows[ln][j] * W2[j * NCLS + c];
    h2s[ln][c] = acc;
    if (n0 + ln < N) h2[(size_t)(n0 + ln) * NCLS + c] = acc;
    __syncthreads();
    if (tid < 48) {
        int l = tid / 3, j = tid - l * 3;
        if (n0 + l < N) {
            float s = 0.f;
#pragma unroll
            for (int cc = 0; cc < NCLS; cc++) s += h2s[l][cc] * a2[j * NCLS + cc];
            d2[j * N + n0 + l] = s;
        }
    }
}

// ---------------------------------------------------------------- layer2 attention CSR, single pass + log_softmax -> out (fp32)
__global__ __launch_bounds__(256) void attn2_csr_kernel(
    const int* __restrict__ csr, const int* __restrict__ start,
    const int* __restrict__ deg, const int* __restrict__ pidx,
    const float* __restrict__ d2, const float* __restrict__ h2,
    const float* __restrict__ b2, const unsigned int* __restrict__ gmax2,
    float* __restrict__ out, int N, int P)
{
    int node = blockIdx.x * 16 + (threadIdx.x >> 4);
    if (node >= N) return;
    int c = threadIdx.x & 15;
    int s0 = start[node], dg = deg[node];
    const float dh = d2[node];
    const float* d2m = d2 + N;
    const float* d2t = d2 + 2 * N;
    float zub = dh + dec_f32(gmax2[0]) + dec_f32(gmax2[1]);
    const float mxub = zub > 0.f ? zub : 0.2f * zub;

    float acc = 0.f, den = 0.f;
    for (int k0 = 0; k0 < dg; k0 += 16) {
        int kk = k0 + c;
        bool valid = kk < dg;
        int p = csr[s0 + (valid ? kk : dg - 1)];
        int mid = pidx[P + p], tl = pidx[2 * P + p];
        float z = dh + d2m[mid] + d2t[tl];
        float e = z > 0.f ? z : 0.2f * z;
        float ex = valid ? __expf(e - mxub) : 0.f;
        den += ex;
        int kmax = dg - k0; if (kmax > 16) kmax = 16;
        for (int dk = 0; dk < kmax; dk++) {
            int tl_b = __shfl(tl, dk, 16);
            float ex_b = __shfl(ex, dk, 16);
            acc += ex_b * h2[(size_t)tl_b * NCLS + c];
        }
    }
#pragma unroll
    for (int w = 1; w < 16; w <<= 1) den += __shfl_xor(den, w, 16);

    float o = acc / (den + 1e-16f) + b2[c];
    // log_softmax across the 16 lanes of this node
    float m2 = o;
#pragma unroll
    for (int w = 1; w < 16; w <<= 1) m2 = fmaxf(m2, __shfl_xor(m2, w, 16));
    float ex = __expf(o - m2), sm = ex;
#pragma unroll
    for (int w = 1; w < 16; w <<= 1) sm += __shfl_xor(sm, w, 16);
    float r = o - m2 - __logf(sm);
    out[(size_t)node * NCLS + c] = r;
}

// ================================================================ launch
extern "C" void kernel_launch(void* const* d_in, const int* in_sizes, int n_in,
                              void* d_out, int out_size, void* d_ws, size_t ws_size,
                              hipStream_t stream)
{
    const float* x  = (const float*)d_in[0];
    const int*   pi = (const int*)d_in[1];
    const float* W1 = (const float*)d_in[2];
    const float* a1 = (const float*)d_in[3];
    const float* b1 = (const float*)d_in[4];
    const float* W2 = (const float*)d_in[5];
    const float* a2 = (const float*)d_in[6];
    const float* b2 = (const float*)d_in[7];

    const int N = in_sizes[0] / F_IN;   // 100000
    const int P = in_sizes[1] / 3;      // 1000000

    float* ws = (float*)d_ws;
    // workspace (float units): peak ~238N + P + 67k floats (~99.5 MB)
    size_t off_h1     = 0;                          // 64N  (bf16 x 128N)
    size_t off_d1     = (size_t)64 * N;             // 24N
    size_t off_elu    = (size_t)88 * N;             // 128N
    size_t off_h2     = (size_t)216 * N;            // 16N
    size_t off_d2     = (size_t)232 * N;            // 3N
    size_t off_deg    = (size_t)235 * N;            // N (int)
    size_t off_start  = (size_t)236 * N;            // N (int)
    size_t off_cursor = (size_t)237 * N;            // N (int)
    size_t off_gmax   = (size_t)238 * N;            // 32 (uint: 16 for d1, 2 for d2)
    size_t off_bsum   = (size_t)238 * N + 32;       // 1024 (int)
    size_t off_csr    = (size_t)238 * N + 32 + 1024; // P (int)
    size_t off_w1th   = off_csr + P;                // 32768 (bf16 x 65536)
    size_t off_w1tl   = off_w1th + 32768;           // 32768

    __hip_bfloat16* h1 = (__hip_bfloat16*)(ws + off_h1);
    float* d1   = ws + off_d1;
    float* elu  = ws + off_elu;
    float* h2   = ws + off_h2;
    float* d2   = ws + off_d2;
    int* deg    = (int*)(ws + off_deg);
    int* start  = (int*)(ws + off_start);
    int* cursor = (int*)(ws + off_cursor);
    unsigned int* gmax  = (unsigned int*)(ws + off_gmax);       // 16
    unsigned int* gmax2 = (unsigned int*)(ws + off_gmax) + 16;  // 2
    int* bsum   = (int*)(ws + off_bsum);
    int* csr    = (int*)(ws + off_csr);
    __bf16* w1t_hi = (__bf16*)(ws + off_w1th);
    __bf16* w1t_lo = (__bf16*)(ws + off_w1tl);

    const int BLK = 256;
    const int nb = (N + 255) / 256;   // scan blocks (<= 512)

    transpose_w1<<<(HC * KPAD) / 256, 256, 0, stream>>>(W1, w1t_hi, w1t_lo);
    // zero deg, start, cursor, gmax (3N + 32 ints contiguous)
    zero_i32<<<(3 * N + 32 + BLK - 1) / BLK, BLK, 0, stream>>>(deg, 3 * N + 32);
    gemm1_mfma<<<(N + 31) / 32, 256, 0, stream>>>(x, w1t_hi, w1t_lo, h1, N);
    dots1_kernel<<<(N * NHEAD + BLK - 1) / BLK, BLK, 0, stream>>>(h1, a1, d1, N);
    maxred_d1<<<1024, 256, 0, stream>>>(d1, gmax, N);
    // CSR build
    hist_kernel<<<(P + BLK - 1) / BLK, BLK, 0, stream>>>(pi, deg, P);
    scan1_kernel<<<nb, 256, 0, stream>>>(deg, start, bsum, N);
    scan2_kernel<<<1, 512, 0, stream>>>(bsum, nb);
    scan3_kernel<<<nb, 256, 0, stream>>>(start, bsum, N);
    scatter_kernel<<<(P + BLK - 1) / BLK, BLK, 0, stream>>>(pi, start, cursor, csr, P);
    // layer 1 attention (single-pass, fused softmax/aggregate/bias/elu)
    attn1_csr_kernel<<<(N + 3) / 4, 256, 0, stream>>>(csr, start, deg, pi, d1, h1, b1, gmax, elu, N, P);
    // layer 2
    layer2_kernel<<<(N + 15) / 16, 256, 0, stream>>>(elu, W2, a2, h2, d2, N);
    maxred_d2<<<256, 256, 0, stream>>>(d2, gmax2, N);
    attn2_csr_kernel<<<(N + 15) / 16, 256, 0, stream>>>(csr, start, deg, pi, d2, h2, b2, gmax2,
                                                        (float*)d_out, N, P);
}